// Round 12
// baseline (258.707 us; speedup 1.0000x reference)
//
#include <hip/hip_runtime.h>

#define IN_F 4096
#define OUT_F 4096
#define NTOK 8192   // B*S = 4*2048
#define KDIM 4096

using i32x4 = __attribute__((ext_vector_type(4))) int;
using f32x4 = __attribute__((ext_vector_type(4))) float;

__device__ __forceinline__ void gload_lds16(const void* g, void* l) {
  __builtin_amdgcn_global_load_lds(
      (const __attribute__((address_space(1))) void*)g,
      (__attribute__((address_space(3))) void*)l, 16, 0, 0);
}

#define WAITV(n) asm volatile("s_waitcnt vmcnt(" #n ")" ::: "memory")

// ---------------- Pass 1: RMSNorm + per-token int8 absmax quant ------------
__global__ __launch_bounds__(256) void rmsq_kernel(
    const float* __restrict__ x, const float* __restrict__ rmsw,
    signed char* __restrict__ q, float* __restrict__ dscale) {
  const int tok = blockIdx.x;
  const int tid = threadIdx.x;
  const f32x4* xr = (const f32x4*)(x + (size_t)tok * IN_F);
  const f32x4* wr = (const f32x4*)rmsw;

  f32x4 v[4];
  float ss = 0.f;
#pragma unroll
  for (int c = 0; c < 4; ++c) {
    v[c] = xr[c * 256 + tid];
    ss += v[c].x * v[c].x + v[c].y * v[c].y + v[c].z * v[c].z + v[c].w * v[c].w;
  }

  __shared__ float red[4];
#pragma unroll
  for (int off = 32; off > 0; off >>= 1) ss += __shfl_down(ss, off, 64);
  const int wid = tid >> 6;
  if ((tid & 63) == 0) red[wid] = ss;
  __syncthreads();
  const float tot = red[0] + red[1] + red[2] + red[3];
  const float rinv = rsqrtf(tot * (1.0f / IN_F) + 1e-6f);

  f32x4 h[4];
  float amax = 0.f;
#pragma unroll
  for (int c = 0; c < 4; ++c) {
    f32x4 w = wr[c * 256 + tid];
    h[c].x = v[c].x * rinv * w.x;
    h[c].y = v[c].y * rinv * w.y;
    h[c].z = v[c].z * rinv * w.z;
    h[c].w = v[c].w * rinv * w.w;
    amax = fmaxf(amax, fabsf(h[c].x));
    amax = fmaxf(amax, fabsf(h[c].y));
    amax = fmaxf(amax, fabsf(h[c].z));
    amax = fmaxf(amax, fabsf(h[c].w));
  }

  __syncthreads();
#pragma unroll
  for (int off = 32; off > 0; off >>= 1)
    amax = fmaxf(amax, __shfl_down(amax, off, 64));
  if ((tid & 63) == 0) red[wid] = amax;
  __syncthreads();
  amax = fmaxf(fmaxf(red[0], red[1]), fmaxf(red[2], red[3]));
  amax = fmaxf(amax, 1e-5f);
  const float qs = 127.0f / amax;
  if (tid == 0) dscale[tok] = amax * (1.0f / 127.0f);

  uint* qo = (uint*)(q + (size_t)tok * IN_F);
#pragma unroll
  for (int c = 0; c < 4; ++c) {
    float r0 = fminf(fmaxf(rintf(h[c].x * qs), -128.f), 127.f);
    float r1 = fminf(fmaxf(rintf(h[c].y * qs), -128.f), 127.f);
    float r2 = fminf(fmaxf(rintf(h[c].z * qs), -128.f), 127.f);
    float r3 = fminf(fmaxf(rintf(h[c].w * qs), -128.f), 127.f);
    uint p = ((uint)((int)r0 & 255)) | ((uint)((int)r1 & 255) << 8) |
             ((uint)((int)r2 & 255) << 16) | ((uint)((int)r3 & 255) << 24);
    qo[c * 256 + tid] = p;
  }
}

// ---------------- Pass 2: W float32 {-1,0,1} -> int8 ----------------------
__global__ __launch_bounds__(256) void wconv_kernel(
    const float* __restrict__ W, signed char* __restrict__ Wq) {
  const int idx = blockIdx.x * 256 + threadIdx.x;
  f32x4 w = ((const f32x4*)W)[idx];
  uint p = ((uint)((int)w.x & 255)) | ((uint)((int)w.y & 255) << 8) |
           ((uint)((int)w.z & 255) << 16) | ((uint)((int)w.w & 255) << 24);
  ((uint*)Wq)[idx] = p;
}

// ---------------- Pass 3: BARRIER-FREE int8 GEMM (1 wave per block) --------
// Block = 1 wave (64 thr), tile 64x128, BK=64. Wave-private LDS buffers
// (A 4KB + B 8KB) x NBUF=3 = 36 KB -> 4 independent waves/CU (1/SIMD),
// ZERO s_barrier in the K-loop: only per-wave counted vmcnt + compiler
// lgkmcnt. Depth-2 prefetch. XCD map: XCD x owns n-blocks 4x..4x+3
// (B = 2 MB/XCD L2-resident); an m-block's 4 n-siblings are consecutive
// bids -> co-resident -> 4x A L2 reuse (FETCH ~ unchanged).
#define BM 64
#define BN 128
#define BK 64
#define NT (KDIM / BK)       // 64 K-tiles
#define ATILEB (BM * BK)     // 4096
#define BTILEB (BN * BK)     // 8192
#define BUFB (ATILEB + BTILEB)  // 12288
#define NBUF 3

__global__ __launch_bounds__(64, 1) void gemm_kernel(
    const signed char* __restrict__ A, const signed char* __restrict__ Bw,
    const float* __restrict__ dscale, const float* __restrict__ bias,
    const float* __restrict__ wscale_p, float* __restrict__ out) {
  __shared__ __align__(16) signed char lds[NBUF * BUFB];  // 36 KB

  const int lane = threadIdx.x;  // 0..63 (block == wave)

  // XCD map: x = bid&7 (hw round-robin); j = bid>>3 in [0,512):
  // m_block = j>>2 (0..127), n_block = x*4 + (j&3)
  const int bid = blockIdx.x;
  const int x = bid & 7;
  const int j = bid >> 3;
  const int m0 = (j >> 2) * BM;
  const int n0 = (x * 4 + (j & 3)) * BN;

  // staging: unit u -> row r=u>>2, phys slot p=u&3 holds logical slot
  // s = p ^ ((r>>1)&3)  (pre-swizzled global source, linear LDS dest)
  // A: 256 units (4/lane); B: 512 units (8/lane)
  const signed char* agp[4];
#pragma unroll
  for (int k = 0; k < 4; ++k) {
    const int u = lane + k * 64;
    const int r = u >> 2;
    const int s = (u & 3) ^ ((r >> 1) & 3);
    agp[k] = A + (size_t)(m0 + r) * KDIM + s * 16;
  }
  const signed char* bgp[8];
#pragma unroll
  for (int k = 0; k < 8; ++k) {
    const int u = lane + k * 64;
    const int r = u >> 2;
    const int s = (u & 3) ^ ((r >> 1) & 3);
    bgp[k] = Bw + (size_t)(n0 + r) * KDIM + s * 16;
  }

#define STAGE(kt, boff)                                                    \
  do {                                                                     \
    const int k0_ = (kt) * BK;                                             \
    signed char* lb_ = &lds[(boff)];                                       \
    gload_lds16(agp[0] + k0_, lb_ + (lane + 0 * 64) * 16);                 \
    gload_lds16(agp[1] + k0_, lb_ + (lane + 1 * 64) * 16);                 \
    gload_lds16(agp[2] + k0_, lb_ + (lane + 2 * 64) * 16);                 \
    gload_lds16(agp[3] + k0_, lb_ + (lane + 3 * 64) * 16);                 \
    gload_lds16(bgp[0] + k0_, lb_ + ATILEB + (lane + 0 * 64) * 16);        \
    gload_lds16(bgp[1] + k0_, lb_ + ATILEB + (lane + 1 * 64) * 16);        \
    gload_lds16(bgp[2] + k0_, lb_ + ATILEB + (lane + 2 * 64) * 16);        \
    gload_lds16(bgp[3] + k0_, lb_ + ATILEB + (lane + 3 * 64) * 16);        \
    gload_lds16(bgp[4] + k0_, lb_ + ATILEB + (lane + 4 * 64) * 16);        \
    gload_lds16(bgp[5] + k0_, lb_ + ATILEB + (lane + 5 * 64) * 16);        \
    gload_lds16(bgp[6] + k0_, lb_ + ATILEB + (lane + 6 * 64) * 16);        \
    gload_lds16(bgp[7] + k0_, lb_ + ATILEB + (lane + 7 * 64) * 16);        \
  } while (0)

  // fragment read offsets (R6 swizzle, measured conflict-free)
  const int fr = lane & 15;
  const int ks = lane >> 4;
  int offA[4], offB[8];
#pragma unroll
  for (int mi = 0; mi < 4; ++mi) {
    const int row = mi * 16 + fr;
    offA[mi] = (row * 4 + (ks ^ ((row >> 1) & 3))) * 16;
  }
#pragma unroll
  for (int ni = 0; ni < 8; ++ni) {
    const int row = ni * 16 + fr;
    offB[ni] = ATILEB + (row * 4 + (ks ^ ((row >> 1) & 3))) * 16;
  }

  i32x4 acc[4][8];
#pragma unroll
  for (int i = 0; i < 4; ++i)
#pragma unroll
    for (int jj = 0; jj < 8; ++jj) acc[i][jj] = (i32x4){0, 0, 0, 0};

  // prologue: depth-2 fill (24 outstanding)
  STAGE(0, 0);
  STAGE(1, BUFB);

  int br = 0;             // buffer holding tile t
  int bs = 2 * BUFB;      // buffer to stage tile t+2 into
  for (int t = 0; t < NT; ++t) {
    // own tile-t loads done; tile t+1 (12) stays in flight. No barrier:
    // single-wave block, vmcnt/lgkmcnt are per-wave.
    if (t < NT - 1) WAITV(12); else WAITV(0);

    const signed char* bp = &lds[br];
    i32x4 af[4], bf[8];
#pragma unroll
    for (int i = 0; i < 4; ++i) af[i] = *(const i32x4*)(bp + offA[i]);
#pragma unroll
    for (int i = 0; i < 8; ++i) bf[i] = *(const i32x4*)(bp + offB[i]);

    if (t + 2 < NT) STAGE(t + 2, bs);

#pragma unroll
    for (int mi = 0; mi < 4; ++mi)
#pragma unroll
      for (int ni = 0; ni < 8; ++ni)
        acc[mi][ni] = __builtin_amdgcn_mfma_i32_16x16x64_i8(af[mi], bf[ni],
                                                            acc[mi][ni], 0, 0, 0);

    br += BUFB; if (br == NBUF * BUFB) br = 0;
    bs += BUFB; if (bs == NBUF * BUFB) bs = 0;
  }

  // epilogue: dequant + bias + weight_scale
  const float wsc = wscale_p[0];
  const int rbase = (lane >> 4) * 4;
  float bv[8];
#pragma unroll
  for (int ni = 0; ni < 8; ++ni) bv[ni] = bias[n0 + ni * 16 + fr];
#pragma unroll
  for (int mi = 0; mi < 4; ++mi) {
#pragma unroll
    for (int r = 0; r < 4; ++r) {
      const int m = m0 + mi * 16 + rbase + r;
      const float ds = dscale[m];
      float* orow = out + (size_t)m * OUT_F + n0;
#pragma unroll
      for (int ni = 0; ni < 8; ++ni) {
        orow[ni * 16 + fr] = ((float)acc[mi][ni][r] * ds + bv[ni]) * wsc;
      }
    }
  }
#undef STAGE
}

extern "C" void kernel_launch(void* const* d_in, const int* in_sizes, int n_in,
                              void* d_out, int out_size, void* d_ws, size_t ws_size,
                              hipStream_t stream) {
  const float* x = (const float*)d_in[0];
  const float* W = (const float*)d_in[1];
  const float* rmsw = (const float*)d_in[2];
  const float* bias = (const float*)d_in[3];
  const float* wscale = (const float*)d_in[4];
  float* out = (float*)d_out;

  signed char* q = (signed char*)d_ws;                     // 32 MB
  signed char* Wq = q + (size_t)NTOK * IN_F;               // 16 MB
  float* dscale = (float*)(Wq + (size_t)OUT_F * IN_F);     // 32 KB

  rmsq_kernel<<<NTOK, 256, 0, stream>>>(x, rmsw, q, dscale);
  wconv_kernel<<<(OUT_F * IN_F / 4) / 256, 256, 0, stream>>>(W, Wq);
  gemm_kernel<<<(NTOK / BM) * (OUT_F / BN), 64, 0, stream>>>(q, Wq, dscale,
                                                             bias, wscale, out);
}

// Round 13
// 176.706 us; speedup vs baseline: 1.4641x; 1.4641x over previous
//
#include <hip/hip_runtime.h>

#define IN_F 4096
#define OUT_F 4096
#define NTOK 8192   // B*S = 4*2048
#define KDIM 4096

using i32x4 = __attribute__((ext_vector_type(4))) int;
using f32x4 = __attribute__((ext_vector_type(4))) float;

__device__ __forceinline__ void gload_lds16(const void* g, void* l) {
  __builtin_amdgcn_global_load_lds(
      (const __attribute__((address_space(1))) void*)g,
      (__attribute__((address_space(3))) void*)l, 16, 0, 0);
}

#define WAITV(n) asm volatile("s_waitcnt vmcnt(" #n ")" ::: "memory")
#define BAR() do { asm volatile("" ::: "memory"); __builtin_amdgcn_s_barrier(); \
                   asm volatile("" ::: "memory"); } while (0)

// -------- Pass 1 (fused): RMSNorm+quant  OR  W f32->i8 convert -------------
// Blocks [0, NTOK): rmsq for token bid. Blocks [NTOK, NTOK+16384): wconv.
// Both 256 threads; merging lets the short wconv pass fill rmsq's tail and
// saves one launch.
__global__ __launch_bounds__(256) void prep_kernel(
    const float* __restrict__ x, const float* __restrict__ rmsw,
    const float* __restrict__ W, signed char* __restrict__ q,
    signed char* __restrict__ Wq, float* __restrict__ dscale) {
  const int tid = threadIdx.x;
  if (blockIdx.x >= NTOK) {
    // ---- wconv part ----
    const int idx = (blockIdx.x - NTOK) * 256 + tid;  // float4 index
    f32x4 w = ((const f32x4*)W)[idx];
    uint p = ((uint)((int)w.x & 255)) | ((uint)((int)w.y & 255) << 8) |
             ((uint)((int)w.z & 255) << 16) | ((uint)((int)w.w & 255) << 24);
    ((uint*)Wq)[idx] = p;
    return;
  }
  // ---- rmsq part ----
  const int tok = blockIdx.x;
  const f32x4* xr = (const f32x4*)(x + (size_t)tok * IN_F);
  const f32x4* wr = (const f32x4*)rmsw;

  f32x4 v[4];
  float ss = 0.f;
#pragma unroll
  for (int c = 0; c < 4; ++c) {
    v[c] = xr[c * 256 + tid];
    ss += v[c].x * v[c].x + v[c].y * v[c].y + v[c].z * v[c].z + v[c].w * v[c].w;
  }

  __shared__ float red[4];
#pragma unroll
  for (int off = 32; off > 0; off >>= 1) ss += __shfl_down(ss, off, 64);
  const int wid = tid >> 6;
  if ((tid & 63) == 0) red[wid] = ss;
  __syncthreads();
  const float tot = red[0] + red[1] + red[2] + red[3];
  const float rinv = rsqrtf(tot * (1.0f / IN_F) + 1e-6f);

  f32x4 h[4];
  float amax = 0.f;
#pragma unroll
  for (int c = 0; c < 4; ++c) {
    f32x4 w = wr[c * 256 + tid];
    h[c].x = v[c].x * rinv * w.x;
    h[c].y = v[c].y * rinv * w.y;
    h[c].z = v[c].z * rinv * w.z;
    h[c].w = v[c].w * rinv * w.w;
    amax = fmaxf(amax, fabsf(h[c].x));
    amax = fmaxf(amax, fabsf(h[c].y));
    amax = fmaxf(amax, fabsf(h[c].z));
    amax = fmaxf(amax, fabsf(h[c].w));
  }

  __syncthreads();
#pragma unroll
  for (int off = 32; off > 0; off >>= 1)
    amax = fmaxf(amax, __shfl_down(amax, off, 64));
  if ((tid & 63) == 0) red[wid] = amax;
  __syncthreads();
  amax = fmaxf(fmaxf(red[0], red[1]), fmaxf(red[2], red[3]));
  amax = fmaxf(amax, 1e-5f);
  const float qs = 127.0f / amax;
  if (tid == 0) dscale[tok] = amax * (1.0f / 127.0f);

  uint* qo = (uint*)(q + (size_t)tok * IN_F);
#pragma unroll
  for (int c = 0; c < 4; ++c) {
    float r0 = fminf(fmaxf(rintf(h[c].x * qs), -128.f), 127.f);
    float r1 = fminf(fmaxf(rintf(h[c].y * qs), -128.f), 127.f);
    float r2 = fminf(fmaxf(rintf(h[c].z * qs), -128.f), 127.f);
    float r3 = fminf(fmaxf(rintf(h[c].w * qs), -128.f), 127.f);
    uint p = ((uint)((int)r0 & 255)) | ((uint)((int)r1 & 255) << 8) |
             ((uint)((int)r2 & 255) << 16) | ((uint)((int)r3 & 255) << 24);
    qo[c * 256 + tid] = p;
  }
}

// ---------------- Pass 2: int8 GEMM (R6 structure, XCD-PAIR mapping) -------
// 128x256 tile, BK=64, 4 waves, 3 LDS bufs (72 KB -> 2 blocks/CU), depth-2
// prefetch, WAITV(6), one barrier/tile — identical to the 150 µs R6 kernel.
// ONLY change: block->(m,n) map. XCD pair p={2p,2p+1} owns n-width 1024
// (4 n-blocks, W hot set 4 MB); the two XCDs split m (32 m-blocks each ->
// q stream per XCD halves to 16 MB). n varies fastest so 4 consecutive
// blocks (co-resident) share one 512 KB q-chunk. Target: FETCH 270->~165 MB.
#define BM 128
#define BN 256
#define BK 64
#define NT (KDIM / BK)       // 64 K-tiles
#define ATILEB (BM * BK)     // 8192
#define BTILEB (BN * BK)     // 16384
#define BUFB (ATILEB + BTILEB)  // 24576
#define NBUF 3

__global__ __launch_bounds__(256, 2) void gemm_kernel(
    const signed char* __restrict__ A, const signed char* __restrict__ Bw,
    const float* __restrict__ dscale, const float* __restrict__ bias,
    const float* __restrict__ wscale_p, float* __restrict__ out) {
  __shared__ __align__(16) signed char lds[NBUF * BUFB];  // 72 KB

  const int tid = threadIdx.x;
  const int lane = tid & 63;
  const int wc = tid >> 6;   // 0..3 : 64 output cols each

  // XCD-pair mapping (1024 blocks; bid&7 = XCD by hw round-robin):
  // pair = x>>1 owns n-blocks [4*pair, 4*pair+4); member x&1 owns m-half.
  const int bid = blockIdx.x;
  const int x = bid & 7;
  const int j = bid >> 3;                        // 0..127
  const int m0 = ((x & 1) * 32 + (j >> 2)) * BM; // 64 m-blocks
  const int n0 = ((x >> 1) * 4 + (j & 3)) * BN;  // 16 n-blocks

  // staging: unit u -> row r=u>>2, phys slot p=u&3 holds logical slot
  // s = p ^ ((r>>1)&3)  (pre-swizzled global source, linear LDS dest)
  const int cA0 = tid, cA1 = tid + 256;          // A: 512 units
  const int rA0 = cA0 >> 2, rA1 = cA1 >> 2;
  const int sA0 = (cA0 & 3) ^ ((rA0 >> 1) & 3);
  const int sA1 = (cA1 & 3) ^ ((rA1 >> 1) & 3);
  const signed char* agp0 = A + (size_t)(m0 + rA0) * KDIM + sA0 * 16;
  const signed char* agp1 = A + (size_t)(m0 + rA1) * KDIM + sA1 * 16;
  // B: 1024 units, rows 0..255
  const signed char* bgp[4];
#pragma unroll
  for (int jj = 0; jj < 4; ++jj) {
    const int rBj = (tid >> 2) + jj * 64;
    const int sBj = (tid & 3) ^ ((rBj >> 1) & 3);
    bgp[jj] = Bw + (size_t)(n0 + rBj) * KDIM + sBj * 16;
  }

#define STAGE(kt, boff)                                                    \
  do {                                                                     \
    const int k0_ = (kt) * BK;                                             \
    signed char* lb_ = &lds[(boff)];                                       \
    gload_lds16(agp0 + k0_, lb_ + cA0 * 16);                               \
    gload_lds16(agp1 + k0_, lb_ + cA1 * 16);                               \
    gload_lds16(bgp[0] + k0_, lb_ + ATILEB + (tid + 0 * 256) * 16);        \
    gload_lds16(bgp[1] + k0_, lb_ + ATILEB + (tid + 1 * 256) * 16);        \
    gload_lds16(bgp[2] + k0_, lb_ + ATILEB + (tid + 2 * 256) * 16);        \
    gload_lds16(bgp[3] + k0_, lb_ + ATILEB + (tid + 3 * 256) * 16);        \
  } while (0)

  // fragment read offsets (R6 swizzle, measured conflict-free)
  const int fr = lane & 15;
  const int ks = lane >> 4;
  int offA[8], offB[4];
#pragma unroll
  for (int mi = 0; mi < 8; ++mi) {
    const int row = mi * 16 + fr;
    offA[mi] = (row * 4 + (ks ^ ((row >> 1) & 3))) * 16;
  }
#pragma unroll
  for (int ni = 0; ni < 4; ++ni) {
    const int row = wc * 64 + ni * 16 + fr;
    offB[ni] = ATILEB + (row * 4 + (ks ^ ((row >> 1) & 3))) * 16;
  }

  i32x4 acc[8][4];
#pragma unroll
  for (int i = 0; i < 8; ++i)
#pragma unroll
    for (int jj = 0; jj < 4; ++jj) acc[i][jj] = (i32x4){0, 0, 0, 0};

  // prologue: depth-2 fill (tile-0 guard is the loop's WAITV(6))
  STAGE(0, 0);
  STAGE(1, BUFB);

  int br = 0;             // buffer holding tile t
  int bs = 2 * BUFB;      // buffer to stage tile t+2 into
  for (int t = 0; t < NT; ++t) {
    if (t < NT - 1) WAITV(6); else WAITV(0);
    BAR();

    const signed char* bp = &lds[br];
    i32x4 af[8], bf[4];
#pragma unroll
    for (int mi = 0; mi < 8; ++mi) af[mi] = *(const i32x4*)(bp + offA[mi]);
#pragma unroll
    for (int ni = 0; ni < 4; ++ni) bf[ni] = *(const i32x4*)(bp + offB[ni]);

    if (t + 2 < NT) STAGE(t + 2, bs);

    __builtin_amdgcn_s_setprio(1);
#pragma unroll
    for (int mi = 0; mi < 8; ++mi)
#pragma unroll
      for (int ni = 0; ni < 4; ++ni)
        acc[mi][ni] = __builtin_amdgcn_mfma_i32_16x16x64_i8(af[mi], bf[ni],
                                                            acc[mi][ni], 0, 0, 0);
    __builtin_amdgcn_s_setprio(0);

    br += BUFB; if (br == NBUF * BUFB) br = 0;
    bs += BUFB; if (bs == NBUF * BUFB) bs = 0;
  }

  // epilogue: dequant + bias + weight_scale
  const float wsc = wscale_p[0];
  const int rbase = (lane >> 4) * 4;
  float bv[4];
#pragma unroll
  for (int ni = 0; ni < 4; ++ni) bv[ni] = bias[n0 + wc * 64 + ni * 16 + fr];
#pragma unroll
  for (int mi = 0; mi < 8; ++mi) {
#pragma unroll
    for (int r = 0; r < 4; ++r) {
      const int m = m0 + mi * 16 + rbase + r;
      const float ds = dscale[m];
      float* orow = out + (size_t)m * OUT_F + n0 + wc * 64;
#pragma unroll
      for (int ni = 0; ni < 4; ++ni) {
        orow[ni * 16 + fr] = ((float)acc[mi][ni][r] * ds + bv[ni]) * wsc;
      }
    }
  }
#undef STAGE
}

extern "C" void kernel_launch(void* const* d_in, const int* in_sizes, int n_in,
                              void* d_out, int out_size, void* d_ws, size_t ws_size,
                              hipStream_t stream) {
  const float* x = (const float*)d_in[0];
  const float* W = (const float*)d_in[1];
  const float* rmsw = (const float*)d_in[2];
  const float* bias = (const float*)d_in[3];
  const float* wscale = (const float*)d_in[4];
  float* out = (float*)d_out;

  signed char* q = (signed char*)d_ws;                     // 32 MB
  signed char* Wq = q + (size_t)NTOK * IN_F;               // 16 MB
  float* dscale = (float*)(Wq + (size_t)OUT_F * IN_F);     // 32 KB

  prep_kernel<<<NTOK + (OUT_F * IN_F / 4) / 256, 256, 0, stream>>>(
      x, rmsw, W, q, Wq, dscale);
  gemm_kernel<<<(NTOK / BM) * (OUT_F / BN), 256, 0, stream>>>(q, Wq, dscale,
                                                              bias, wscale, out);
}